// Round 5
// baseline (581.299 us; speedup 1.0000x reference)
//
#include <hip/hip_runtime.h>

// ShootingBlockMNModel1 — multi-kernel, contention-free partial reductions.
// part layout is COLUMN-MAJOR per row: part[row][col][NB] (col in 0..35),
// so per-column folds are wave-coalesced contiguous reads.
//
// ws layout (floats), NB = reduce grid size:
//   part  [21][36][NB] @ 0
//   sums  [21][36]
//   theta [21][12]
//   pk    [20][20]      (packed theta_k + lam_{k+1} for k_final)
//   ksym  [16], ksymb[4]

#define LR 0.25f
#define NIT 20
#define RTPB 512

__device__ __forceinline__ float fast_tanh(float x){
    float e = __expf(2.0f*x);
    return 1.0f - 2.0f/(e+1.0f);
}

__device__ __forceinline__ void compute_grad(const float* __restrict__ s,
                                             const float* __restrict__ th,
                                             const float* __restrict__ ksym,
                                             const float* __restrict__ ksymb,
                                             float c, float* g){
    const float Ivec[4]={1.f,0.f,0.f,1.f};
    #pragma unroll
    for(int j=0;j<4;j++){
        float kv=0.f;
        #pragma unroll
        for(int m=0;m<4;m++) kv += ksym[j*4+m]*th[m];
        g[j] = kv - c*s[j];
    }
    #pragma unroll
    for(int i2=0;i2<2;i2++)
        g[4+i2] = ksymb[i2*2+0]*th[4] + ksymb[i2*2+1]*th[5] - c*s[4+i2];
    #pragma unroll
    for(int j=0;j<4;j++){
        float kv=0.f;
        #pragma unroll
        for(int m=0;m<4;m++) kv += ksym[j*4+m]*(th[6+m]-Ivec[m]);
        g[6+j] = kv - c*s[6+j];
    }
    #pragma unroll
    for(int i2=0;i2<2;i2++)
        g[10+i2] = ksymb[i2*2+0]*th[10] + ksymb[i2*2+1]*th[11] - c*s[10+i2];
}

__global__ void k_setup(const float* __restrict__ t1i, const float* __restrict__ b1i,
                        const float* __restrict__ t2i, const float* __restrict__ b2i,
                        const float* __restrict__ invK, const float* __restrict__ invKb,
                        float* __restrict__ theta, float* __restrict__ ksym,
                        float* __restrict__ ksymb){
    if(threadIdx.x==0 && blockIdx.x==0){
        theta[0]=t1i[0]; theta[1]=t1i[1]; theta[2]=t1i[2]; theta[3]=t1i[3];
        theta[4]=b1i[0]; theta[5]=b1i[1];
        theta[6]=t2i[0]; theta[7]=t2i[1]; theta[8]=t2i[2]; theta[9]=t2i[3];
        theta[10]=b2i[0]; theta[11]=b2i[1];
        for(int a=0;a<4;a++)
            for(int b=0;b<4;b++)
                ksym[a*4+b] = 0.5f*(invK[a*4+b]+invK[b*4+a]);
        for(int a=0;a<2;a++)
            for(int b=0;b<2;b++)
                ksymb[a*2+b] = 0.5f*(invKb[a*2+b]+invKb[b*2+a]);
    }
}

__device__ __forceinline__ void accum_sample(float q0,float q1,float p0,float p1,
    float t1_00,float t1_01,float t1_10,float t1_11,
    float t2_00,float t2_01,float t2_10,float t2_11,float b2_0,float b2_1,
    float (&acc)[36]){
    float u0 = t2_00*q0 + t2_01*q1 + b2_0;
    float u1 = t2_10*q0 + t2_11*q1 + b2_1;
    float h0 = fast_tanh(u0), h1 = fast_tanh(u1);
    float s0 = 1.0f-h0*h0, s1 = 1.0f-h1*h1;
    float a0 = t1_00*p0 + t1_10*p1;      // (T1^T p)
    float a1 = t1_01*p0 + t1_11*p1;
    float w0 = a0*s0, w1 = a1*s1;
    float r0 = -2.0f*a0*h0*s0, r1 = -2.0f*a1*h1*s1;
    acc[0]+=p0*h0; acc[1]+=p0*h1; acc[2]+=p1*h0; acc[3]+=p1*h1;
    acc[4]+=p0;    acc[5]+=p1;
    acc[6]+=w0*q0; acc[7]+=w0*q1; acc[8]+=w1*q0; acc[9]+=w1*q1;
    acc[10]+=w0;   acc[11]+=w1;
    float ps00=p0*s0, ps01=p0*s1, ps10=p1*s0, ps11=p1*s1;
    acc[12]+=ps00*q0; acc[13]+=ps00*q1; acc[14]+=ps01*q0; acc[15]+=ps01*q1;
    acc[16]+=ps10*q0; acc[17]+=ps10*q1; acc[18]+=ps11*q0; acc[19]+=ps11*q1;
    acc[20]+=ps00; acc[21]+=ps01; acc[22]+=ps10; acc[23]+=ps11;
    float r0q0=r0*q0, r1q0=r1*q0;
    acc[24]+=r0q0*q0; acc[25]+=r0q0*q1; acc[26]+=r0*q1*q1;
    acc[27]+=r1q0*q0; acc[28]+=r1q0*q1; acc[29]+=r1*q1*q1;
    acc[30]+=r0q0; acc[31]+=r0*q1; acc[32]+=r1q0; acc[33]+=r1*q1;
    acc[34]+=r0; acc[35]+=r1;
}

__global__ __launch_bounds__(RTPB, 4) void k_reduce(
    const float4* __restrict__ q4, const float4* __restrict__ p4, int nv4,
    const float* __restrict__ theta_prev,   // row k-1 (row 0 when k==0)
    const float* __restrict__ part_prev,    // row k-1 [36][NB], nullptr when k==0
    int NB,
    float* __restrict__ part_out,           // row k [36][NB]
    float* __restrict__ theta_out,          // row k (block 0 persists)
    const float* __restrict__ ksym_g, const float* __restrict__ ksymb_g,
    float c)
{
    const int tid = threadIdx.x;
    const int NT = gridDim.x*RTPB;
    const int gtid = blockIdx.x*RTPB + tid;

    __shared__ float ths[12];
    __shared__ float sgv[12];
    __shared__ float tsum[12][33];
    __shared__ float red[RTPB/64][36];

    // prefetch first two slices (independent of theta)
    float4 qa, pa, qb, pb;
    bool va = (gtid < nv4), vb = (gtid + NT < nv4);
    if(va){ qa = q4[gtid]; pa = p4[gtid]; }
    if(vb){ qb = q4[gtid+NT]; pb = p4[gtid+NT]; }

    // ---- theta recompute (redundant per block); cols 0..11 of prev row ----
    if(part_prev){
        if(tid < 12*32){
            int j = tid >> 5, ch = tid & 31;
            const float* col = part_prev + j*NB;
            float s = 0.f;
            for(int i = ch; i < NB; i += 32) s += col[i];   // wave-coalesced
            tsum[j][ch] = s;
        }
        __syncthreads();
        if(tid < 12){
            float s = 0.f;
            #pragma unroll
            for(int ch=0; ch<32; ch++) s += tsum[tid][ch];
            sgv[tid] = s;
        }
        __syncthreads();
        if(tid == 0){
            float g[12], tp[12];
            #pragma unroll
            for(int j=0;j<12;j++) tp[j] = theta_prev[j];
            compute_grad(sgv, tp, ksym_g, ksymb_g, c, g);
            #pragma unroll
            for(int j=0;j<12;j++){
                float t = tp[j] - LR*g[j];
                ths[j] = t;
                if(blockIdx.x==0) theta_out[j] = t;
            }
        }
    }else{
        if(tid < 12) ths[tid] = theta_prev[tid];
    }
    __syncthreads();

    const float t1_00=ths[0], t1_01=ths[1], t1_10=ths[2], t1_11=ths[3];
    const float t2_00=ths[6], t2_01=ths[7], t2_10=ths[8], t2_11=ths[9];
    const float b2_0=ths[10], b2_1=ths[11];

    float acc[36];
    #pragma unroll
    for(int j=0;j<36;j++) acc[j]=0.0f;
    if(va){
        accum_sample(qa.x,qa.y,pa.x,pa.y,
                     t1_00,t1_01,t1_10,t1_11,t2_00,t2_01,t2_10,t2_11,b2_0,b2_1,acc);
        accum_sample(qa.z,qa.w,pa.z,pa.w,
                     t1_00,t1_01,t1_10,t1_11,t2_00,t2_01,t2_10,t2_11,b2_0,b2_1,acc);
    }
    if(vb){
        accum_sample(qb.x,qb.y,pb.x,pb.y,
                     t1_00,t1_01,t1_10,t1_11,t2_00,t2_01,t2_10,t2_11,b2_0,b2_1,acc);
        accum_sample(qb.z,qb.w,pb.z,pb.w,
                     t1_00,t1_01,t1_10,t1_11,t2_00,t2_01,t2_10,t2_11,b2_0,b2_1,acc);
    }
    for(int j = gtid + 2*NT; j < nv4; j += NT){
        float4 qq = q4[j], pp = p4[j];
        accum_sample(qq.x,qq.y,pp.x,pp.y,
                     t1_00,t1_01,t1_10,t1_11,t2_00,t2_01,t2_10,t2_11,b2_0,b2_1,acc);
        accum_sample(qq.z,qq.w,pp.z,pp.w,
                     t1_00,t1_01,t1_10,t1_11,t2_00,t2_01,t2_10,t2_11,b2_0,b2_1,acc);
    }

    const int lane = tid & 63, wave = tid >> 6;
    #pragma unroll
    for(int j=0;j<36;j++){
        float v = acc[j];
        v += __shfl_down(v,32); v += __shfl_down(v,16); v += __shfl_down(v,8);
        v += __shfl_down(v,4);  v += __shfl_down(v,2);  v += __shfl_down(v,1);
        if(lane==0) red[wave][j]=v;
    }
    __syncthreads();
    if(tid < 36){
        float sum = 0.f;
        #pragma unroll
        for(int w=0; w<RTPB/64; w++) sum += red[w][tid];
        part_out[tid*NB + blockIdx.x] = sum;   // column-major, no atomics
    }
}

// One block per row: fold [36][NB] -> sums[row][36]. Coalesced per column.
__global__ __launch_bounds__(288) void k_fold(
    const float* __restrict__ part, int NB, float* __restrict__ sums)
{
    const int row = blockIdx.x;
    const int tid = threadIdx.x;            // 288 = 36 cols x 8 chunks
    const int col = tid >> 3, ch = tid & 7;
    __shared__ float fr[36][9];
    const float* base = part + (size_t)row*36*NB + col*NB;
    float s = 0.f;
    for(int i = ch; i < NB; i += 8) s += base[i];
    fr[col][ch] = s;
    __syncthreads();
    if(tid < 36){
        float t = 0.f;
        #pragma unroll
        for(int j=0;j<8;j++) t += fr[tid][j];
        sums[row*36 + tid] = t;
    }
}

// Serial 12-dim adjoint recursion on folded sums; packs pk[k].
__global__ void k_backward(
    const float* __restrict__ sums,         // [21][36]
    const float* __restrict__ thetaAll,     // [21][12]
    float* __restrict__ pk_g,               // [20][20]
    const float* __restrict__ ksym, const float* __restrict__ ksymb, float c)
{
    if(threadIdx.x!=0 || blockIdx.x!=0) return;
    float lv[12];
    compute_grad(sums + 20*36, thetaAll + 20*12, ksym, ksymb, c, lv);
    for(int k=NIT-1;k>=0;k--){
        const float* s = sums + k*36;
        const float* T = thetaAll + k*12;
        float* P = pk_g + k*20;
        P[0]=T[0]; P[1]=T[1]; P[2]=T[2]; P[3]=T[3];        // T1
        P[4]=T[6]; P[5]=T[7]; P[6]=T[8]; P[7]=T[9];        // T2
        P[8]=T[10]; P[9]=T[11];                            // b2
        P[10]=lv[0]; P[11]=lv[1]; P[12]=lv[2]; P[13]=lv[3];// Lam1_{k+1}
        P[14]=lv[6]; P[15]=lv[7]; P[16]=lv[8]; P[17]=lv[9];// Lam2_{k+1}
        P[18]=lv[10]; P[19]=lv[11];                        // lb2_{k+1}
        float H[12];
        for(int a=0;a<2;a++)for(int b=0;b<2;b++){
            int j=a*2+b;
            float data = s[12+a*4+b*2+0]*lv[6+b*2+0]
                       + s[12+a*4+b*2+1]*lv[6+b*2+1]
                       + s[20+a*2+b]*lv[10+b];
            float kv=0.f;
            for(int m=0;m<4;m++) kv += ksym[j*4+m]*lv[m];
            H[j]=kv - c*data;
        }
        H[4] = ksymb[0]*lv[4] + ksymb[1]*lv[5];
        H[5] = ksymb[2]*lv[4] + ksymb[3]*lv[5];
        for(int cc=0;cc<2;cc++)for(int d=0;d<2;d++){
            int j=cc*2+d;
            float term1 = lv[0+cc]*s[12+0*4+cc*2+d] + lv[2+cc]*s[12+1*4+cc*2+d];
            float term2 = lv[6+cc*2+0]*s[24+cc*3+(0+d)] + lv[6+cc*2+1]*s[24+cc*3+(1+d)];
            float term3 = lv[10+cc]*s[30+cc*2+d];
            float kv=0.f;
            for(int m=0;m<4;m++) kv += ksym[j*4+m]*lv[6+m];
            H[6+j]=kv - c*(term1+term2+term3);
        }
        for(int cc=0;cc<2;cc++){
            float z1 = lv[0+cc]*s[20+0*2+cc] + lv[2+cc]*s[20+1*2+cc];
            float z2 = lv[6+cc*2+0]*s[30+cc*2+0] + lv[6+cc*2+1]*s[30+cc*2+1];
            float z3 = lv[10+cc]*s[34+cc];
            float kv = ksymb[cc*2+0]*lv[10] + ksymb[cc*2+1]*lv[11];
            H[10+cc]=kv - c*(z1+z2+z3);
        }
        for(int j=0;j<12;j++) lv[j] -= LR*H[j];
    }
}

__device__ __forceinline__ void bk_step(float q0,float q1,float p0,float p1,
    float t1_00,float t1_01,float t1_10,float t1_11,
    float t2_00,float t2_01,float t2_10,float t2_11,float b2_0,float b2_1,
    float L1_00,float L1_01,float L1_10,float L1_11,
    float L2_00,float L2_01,float L2_10,float L2_11,float lb2_0,float lb2_1,
    float &B0, float &B1){
    float u0=t2_00*q0+t2_01*q1+b2_0;
    float u1=t2_10*q0+t2_11*q1+b2_1;
    float h0=fast_tanh(u0), h1=fast_tanh(u1);
    float s0=1.f-h0*h0, s1=1.f-h1*h1;
    float a0=t1_00*p0+t1_10*p1;
    float a1=t1_01*p0+t1_11*p1;
    float w0=a0*s0, w1=a1*s1;
    float r0=-2.f*a0*h0*s0, r1=-2.f*a1*h1*s1;
    float lp0=L1_00*p0+L1_10*p1;
    float lp1=L1_01*p0+L1_11*p1;
    float z0=L2_00*q0+L2_01*q1+lb2_0;
    float z1=L2_10*q0+L2_11*q1+lb2_1;
    float m0=lp0*s0 + r0*z0;
    float m1=lp1*s1 + r1*z1;
    B0 += t2_00*m0 + t2_10*m1 + L2_00*w0 + L2_10*w1;
    B1 += t2_01*m0 + t2_11*m1 + L2_01*w0 + L2_11*w1;
}

__global__ __launch_bounds__(256, 4) void k_final(
    const float4* __restrict__ q4, const float4* __restrict__ p4,
    const float4* __restrict__ x4, int nv4,
    const float4* __restrict__ pk4,       // [NIT][5]
    const float4* __restrict__ th20_4,    // [3] theta row 20
    float4* __restrict__ oq, float4* __restrict__ op, float4* __restrict__ ox,
    float c)
{
    __shared__ float4 pkS[NIT*5];
    __shared__ float4 t20[3];
    for(int j=threadIdx.x;j<NIT*5;j+=blockDim.x) pkS[j]=pk4[j];
    if(threadIdx.x<3) t20[threadIdx.x]=th20_4[threadIdx.x];
    __syncthreads();

    const int NT = gridDim.x*blockDim.x;
    const int j1 = blockIdx.x*blockDim.x + threadIdx.x;
    const int j2 = j1 + NT;
    const bool v1 = (j1 < nv4), v2 = (j2 < nv4);

    float4 qq1, pp1, qq2, pp2;
    if(v1){ qq1=q4[j1]; pp1=p4[j1]; }
    if(v2){ qq2=q4[j2]; pp2=p4[j2]; }

    float A0=0.f,A1=0.f,B0=0.f,B1=0.f;   // slice 1 halves
    float C0=0.f,C1=0.f,D0=0.f,D1=0.f;   // slice 2 halves
    #pragma unroll 2                      // keep loop body << 32 KiB I-cache
    for(int k=0;k<NIT;k++){
        float4 P0=pkS[k*5+0], P1=pkS[k*5+1], P2=pkS[k*5+2], P3=pkS[k*5+3], P4v=pkS[k*5+4];
        float t1_00=P0.x,t1_01=P0.y,t1_10=P0.z,t1_11=P0.w;
        float t2_00=P1.x,t2_01=P1.y,t2_10=P1.z,t2_11=P1.w;
        float b2_0=P2.x,b2_1=P2.y;
        float L1_00=P2.z,L1_01=P2.w,L1_10=P3.x,L1_11=P3.y;
        float L2_00=P3.z,L2_01=P3.w,L2_10=P4v.x,L2_11=P4v.y,lb2_0=P4v.z,lb2_1=P4v.w;
        if(v1){
            bk_step(qq1.x,qq1.y,pp1.x,pp1.y,
                    t1_00,t1_01,t1_10,t1_11,t2_00,t2_01,t2_10,t2_11,b2_0,b2_1,
                    L1_00,L1_01,L1_10,L1_11,L2_00,L2_01,L2_10,L2_11,lb2_0,lb2_1,A0,A1);
            bk_step(qq1.z,qq1.w,pp1.z,pp1.w,
                    t1_00,t1_01,t1_10,t1_11,t2_00,t2_01,t2_10,t2_11,b2_0,b2_1,
                    L1_00,L1_01,L1_10,L1_11,L2_00,L2_01,L2_10,L2_11,lb2_0,lb2_1,B0,B1);
        }
        if(v2){
            bk_step(qq2.x,qq2.y,pp2.x,pp2.y,
                    t1_00,t1_01,t1_10,t1_11,t2_00,t2_01,t2_10,t2_11,b2_0,b2_1,
                    L1_00,L1_01,L1_10,L1_11,L2_00,L2_01,L2_10,L2_11,lb2_0,lb2_1,C0,C1);
            bk_step(qq2.z,qq2.w,pp2.z,pp2.w,
                    t1_00,t1_01,t1_10,t1_11,t2_00,t2_01,t2_10,t2_11,b2_0,b2_1,
                    L1_00,L1_01,L1_10,L1_11,L2_00,L2_01,L2_10,L2_11,lb2_0,lb2_1,D0,D1);
        }
    }

    // epilogue at Theta_20
    float4 Ta=t20[0], Tb=t20[1], Tc=t20[2];
    float t1_00=Ta.x,t1_01=Ta.y,t1_10=Ta.z,t1_11=Ta.w,b1_0=Tb.x,b1_1=Tb.y;
    float t2_00=Tb.z,t2_01=Tb.w,t2_10=Tc.x,t2_11=Tc.y,b2_0=Tc.z,b2_1=Tc.w;

    #pragma unroll
    for(int sl=0; sl<2; sl++){
        bool v = sl? v2 : v1;
        if(!v) continue;
        int j = sl? j2 : j1;
        float4 qq = sl? qq2 : qq1;
        float4 pp = sl? pp2 : pp1;
        float Ba0 = sl? C0 : A0, Ba1 = sl? C1 : A1;
        float Bb0 = sl? D0 : B0, Bb1 = sl? D1 : B1;
        float dq[4], dp[4];
        {
            float u0=t2_00*qq.x+t2_01*qq.y+b2_0;
            float u1=t2_10*qq.x+t2_11*qq.y+b2_1;
            float h0=fast_tanh(u0), h1=fast_tanh(u1);
            float s0=1.f-h0*h0, s1=1.f-h1*h1;
            float a0=t1_00*pp.x+t1_10*pp.y;
            float a1=t1_01*pp.x+t1_11*pp.y;
            float w0=a0*s0, w1=a1*s1;
            dq[0]=t1_00*h0 + t1_01*h1 + b1_0;
            dq[1]=t1_10*h0 + t1_11*h1 + b1_1;
            dp[0]=c*(LR*Ba0 - (t2_00*w0 + t2_10*w1));
            dp[1]=c*(LR*Ba1 - (t2_01*w0 + t2_11*w1));
        }
        {
            float u0=t2_00*qq.z+t2_01*qq.w+b2_0;
            float u1=t2_10*qq.z+t2_11*qq.w+b2_1;
            float h0=fast_tanh(u0), h1=fast_tanh(u1);
            float s0=1.f-h0*h0, s1=1.f-h1*h1;
            float a0=t1_00*pp.z+t1_10*pp.w;
            float a1=t1_01*pp.z+t1_11*pp.w;
            float w0=a0*s0, w1=a1*s1;
            dq[2]=t1_00*h0 + t1_01*h1 + b1_0;
            dq[3]=t1_10*h0 + t1_11*h1 + b1_1;
            dp[2]=c*(LR*Bb0 - (t2_00*w0 + t2_10*w1));
            dp[3]=c*(LR*Bb1 - (t2_01*w0 + t2_11*w1));
        }
        oq[j] = make_float4(dq[0],dq[1],dq[2],dq[3]);
        op[j] = make_float4(dp[0],dp[1],dp[2],dp[3]);
        float4 xx = x4[j];
        float xu0=t2_00*xx.x+t2_01*xx.y+b2_0;
        float xu1=t2_10*xx.x+t2_11*xx.y+b2_1;
        float xv0=t2_00*xx.z+t2_01*xx.w+b2_0;
        float xv1=t2_10*xx.z+t2_11*xx.w+b2_1;
        float xh0=fast_tanh(xu0), xh1=fast_tanh(xu1);
        float xh2=fast_tanh(xv0), xh3=fast_tanh(xv1);
        ox[j] = make_float4(t1_00*xh0 + t1_01*xh1 + b1_0,
                            t1_10*xh0 + t1_11*xh1 + b1_1,
                            t1_00*xh2 + t1_01*xh3 + b1_0,
                            t1_10*xh2 + t1_11*xh3 + b1_1);
    }
}

extern "C" void kernel_launch(void* const* d_in, const int* in_sizes, int n_in,
                              void* d_out, int out_size, void* d_ws, size_t ws_size,
                              hipStream_t stream) {
    const float* inp = (const float*)d_in[1];
    const int K = in_sizes[1]/6;
    const int nv4 = K >> 1;                    // float4 count per q/p/x section

    const float4* q4 = (const float4*)inp;
    const float4* p4 = (const float4*)(inp + 2*(size_t)K);
    const float4* x4 = (const float4*)(inp + 4*(size_t)K);

    // reduce grid size NB (blocks); shrink if ws too small
    int NB = 512;
    {
        size_t avail_f = ws_size/4;
        size_t fixed = 756 + 252 + NIT*20 + 16 + 4 + 64;
        while(NB > 128 && (size_t)(NIT+1)*36*NB + fixed > avail_f) NB >>= 1;
    }

    float* part  = (float*)d_ws;                                   // [21][36][NB]
    float* sums  = part + (size_t)(NIT+1)*36*NB;                   // [21][36]
    float* theta = sums + 756;                                     // [21][12]
    float* pk    = theta + 252;                                    // [20][20]
    float* ksym  = pk + NIT*20;                                    // [16]
    float* ksymb = ksym + 16;                                      // [4]
    const float c = 1.0f/(2.0f*(float)K);

    k_setup<<<1,64,0,stream>>>((const float*)d_in[2],(const float*)d_in[3],
                               (const float*)d_in[4],(const float*)d_in[5],
                               (const float*)d_in[6],(const float*)d_in[7],
                               theta, ksym, ksymb);

    for(int k=0;k<=NIT;k++){
        const float* th_prev = (k==0) ? theta : theta + (k-1)*12;
        const float* pt_prev = (k==0) ? nullptr : part + (size_t)(k-1)*36*NB;
        k_reduce<<<NB,RTPB,0,stream>>>(q4, p4, nv4,
                                       th_prev, pt_prev, NB,
                                       part + (size_t)k*36*NB, theta + k*12,
                                       ksym, ksymb, c);
    }
    k_fold<<<NIT+1,288,0,stream>>>(part, NB, sums);
    k_backward<<<1,64,0,stream>>>(sums, theta, pk, ksym, ksymb, c);

    float* out = (float*)d_out;
    int fthreads = (nv4 + 1)/2;
    int fblk = (fthreads + 255)/256;
    k_final<<<fblk,256,0,stream>>>(q4, p4, x4, nv4,
                                   (const float4*)pk, (const float4*)(theta + NIT*12),
                                   (float4*)out, (float4*)(out + 2*(size_t)K),
                                   (float4*)(out + 4*(size_t)K), c);
}

// Round 6
// 281.919 us; speedup vs baseline: 2.0619x; 2.0619x over previous
//
#include <hip/hip_runtime.h>

// ShootingBlockMNModel1 — packed-f32 (v_pk_*) math, rcp-based tanh (no IEEE div),
// DPP wave reduction (no DS-pipe shuffles), contention-free partials.
//
// ws (floats), NB=256 reduce blocks:
//   part  [21][36][NB] @ 0   (each pass fully overwrites its row; no memset)
//   theta [21][12]
//   pk    [20][20]           (packed theta_k + lam_{k+1} for k_final)

#define LR 0.25f
#define NIT 20
#define RTPB 512
#define NBR 256

typedef float v2f __attribute__((ext_vector_type(2)));

__device__ __forceinline__ v2f tanh2(v2f x){
    v2f e;
    e.x = __expf(x.x + x.x);
    e.y = __expf(x.y + x.y);
    v2f d = e + 1.0f;
    v2f r;
    r.x = __builtin_amdgcn_rcpf(d.x);
    r.y = __builtin_amdgcn_rcpf(d.y);
    return 1.0f - (r + r);
}

// wave64 sum via DPP on the VALU pipe; result valid in lane 63
#define DPP_ADD(x, ctrl) ((x) + __int_as_float(__builtin_amdgcn_update_dpp(0, __float_as_int(x), (ctrl), 0xF, 0xF, true)))
__device__ __forceinline__ float wave_sum64(float x){
    x = DPP_ADD(x, 0x111);   // row_shr:1
    x = DPP_ADD(x, 0x112);   // row_shr:2
    x = DPP_ADD(x, 0x114);   // row_shr:4
    x = DPP_ADD(x, 0x118);   // row_shr:8  -> lane 15+16r = row sum
    x = DPP_ADD(x, 0x142);   // row_bcast:15
    x = DPP_ADD(x, 0x143);   // row_bcast:31 -> lane 63 = total
    return x;
}

__device__ __forceinline__ void compute_grad(const float* s, const float* th,
                                             const float* ksym, const float* ksymb,
                                             float c, float* g){
    const float Ivec[4]={1.f,0.f,0.f,1.f};
    #pragma unroll
    for(int j=0;j<4;j++){
        float kv=0.f;
        #pragma unroll
        for(int m=0;m<4;m++) kv += ksym[j*4+m]*th[m];
        g[j] = kv - c*s[j];
    }
    #pragma unroll
    for(int i2=0;i2<2;i2++)
        g[4+i2] = ksymb[i2*2+0]*th[4] + ksymb[i2*2+1]*th[5] - c*s[4+i2];
    #pragma unroll
    for(int j=0;j<4;j++){
        float kv=0.f;
        #pragma unroll
        for(int m=0;m<4;m++) kv += ksym[j*4+m]*(th[6+m]-Ivec[m]);
        g[6+j] = kv - c*s[6+j];
    }
    #pragma unroll
    for(int i2=0;i2<2;i2++)
        g[10+i2] = ksymb[i2*2+0]*th[10] + ksymb[i2*2+1]*th[11] - c*s[10+i2];
}

// packed accumulate: float4 = 2 samples in v2f lanes
__device__ __forceinline__ void accum_sample2(v2f Q0, v2f Q1, v2f P0, v2f P1,
    float t1_00,float t1_01,float t1_10,float t1_11,
    float t2_00,float t2_01,float t2_10,float t2_11,float b2_0,float b2_1,
    v2f (&acc)[36]){
    v2f u0 = t2_00*Q0 + t2_01*Q1 + b2_0;
    v2f u1 = t2_10*Q0 + t2_11*Q1 + b2_1;
    v2f h0 = tanh2(u0), h1 = tanh2(u1);
    v2f s0 = 1.0f - h0*h0, s1 = 1.0f - h1*h1;
    v2f a0 = t1_00*P0 + t1_10*P1;
    v2f a1 = t1_01*P0 + t1_11*P1;
    v2f w0 = a0*s0, w1 = a1*s1;
    v2f r0 = -2.0f*(a0*h0)*s0, r1 = -2.0f*(a1*h1)*s1;
    acc[0]+=P0*h0; acc[1]+=P0*h1; acc[2]+=P1*h0; acc[3]+=P1*h1;
    acc[4]+=P0;    acc[5]+=P1;
    acc[6]+=w0*Q0; acc[7]+=w0*Q1; acc[8]+=w1*Q0; acc[9]+=w1*Q1;
    acc[10]+=w0;   acc[11]+=w1;
    v2f ps00=P0*s0, ps01=P0*s1, ps10=P1*s0, ps11=P1*s1;
    acc[12]+=ps00*Q0; acc[13]+=ps00*Q1; acc[14]+=ps01*Q0; acc[15]+=ps01*Q1;
    acc[16]+=ps10*Q0; acc[17]+=ps10*Q1; acc[18]+=ps11*Q0; acc[19]+=ps11*Q1;
    acc[20]+=ps00; acc[21]+=ps01; acc[22]+=ps10; acc[23]+=ps11;
    v2f r0q0=r0*Q0, r1q0=r1*Q0;
    acc[24]+=r0q0*Q0; acc[25]+=r0q0*Q1; acc[26]+=r0*(Q1*Q1);
    acc[27]+=r1q0*Q0; acc[28]+=r1q0*Q1; acc[29]+=r1*(Q1*Q1);
    acc[30]+=r0q0; acc[31]+=r0*Q1; acc[32]+=r1q0; acc[33]+=r1*Q1;
    acc[34]+=r0; acc[35]+=r1;
}

__global__ __launch_bounds__(RTPB) void k_reduce(
    const float4* __restrict__ q4, const float4* __restrict__ p4, int nv4,
    const float* __restrict__ t1i, const float* __restrict__ b1i,
    const float* __restrict__ t2i, const float* __restrict__ b2i,
    const float* __restrict__ invK, const float* __restrict__ invKb,
    const float* __restrict__ theta_prev,   // row k-1 (unused when k==0)
    const float* __restrict__ part_prev,    // row k-1 [36][NBR], nullptr when k==0
    float* __restrict__ part_out,           // row k [36][NBR]
    float* __restrict__ theta_out,          // row k (block 0 persists)
    float c)
{
    const int tid = threadIdx.x;
    const int NT = gridDim.x*RTPB;
    const int gtid = blockIdx.x*RTPB + tid;

    __shared__ float ths[12];
    __shared__ float sgv[12];
    __shared__ float tsum[12][33];
    __shared__ float red[RTPB/64][36];
    __shared__ float ks[16], ksb[4];

    if(!part_prev){
        if(tid < 12){
            float v = (tid<4)? t1i[tid] : (tid<6)? b1i[tid-4]
                    : (tid<10)? t2i[tid-6] : b2i[tid-10];
            ths[tid] = v;
            if(blockIdx.x==0) theta_out[tid] = v;
        }
        __syncthreads();
    }else{
        if(tid < 16) ks[tid]  = 0.5f*(invK[tid]  + invK[(tid&3)*4 + (tid>>2)]);
        if(tid < 4)  ksb[tid] = 0.5f*(invKb[tid] + invKb[(tid&1)*2 + (tid>>1)]);
        if(tid < 12*32){
            int j = tid >> 5, ch = tid & 31;
            const float* col = part_prev + j*NBR;
            float s = 0.f;
            #pragma unroll
            for(int i = 0; i < NBR/32; i++) s += col[ch + i*32];
            tsum[j][ch] = s;
        }
        __syncthreads();
        if(tid < 12){
            float s = 0.f;
            #pragma unroll
            for(int ch=0; ch<32; ch++) s += tsum[tid][ch];
            sgv[tid] = s;
        }
        __syncthreads();
        if(tid == 0){
            float g[12], tp[12];
            #pragma unroll
            for(int j=0;j<12;j++) tp[j] = theta_prev[j];
            compute_grad(sgv, tp, ks, ksb, c, g);
            #pragma unroll
            for(int j=0;j<12;j++){
                float t = tp[j] - LR*g[j];
                ths[j] = t;
                if(blockIdx.x==0) theta_out[j] = t;
            }
        }
        __syncthreads();
    }

    const float t1_00=ths[0], t1_01=ths[1], t1_10=ths[2], t1_11=ths[3];
    const float t2_00=ths[6], t2_01=ths[7], t2_10=ths[8], t2_11=ths[9];
    const float b2_0=ths[10], b2_1=ths[11];

    v2f acc[36];
    #pragma unroll
    for(int j=0;j<36;j++) acc[j] = (v2f){0.f, 0.f};

    if(nv4 == 4*NT){   // fast path: exactly 4 slices, loads issued up front
        float4 qd[4], pd[4];
        #pragma unroll
        for(int s=0;s<4;s++){ qd[s]=q4[gtid + s*NT]; pd[s]=p4[gtid + s*NT]; }
        #pragma unroll
        for(int s=0;s<4;s++){
            v2f Q0={qd[s].x,qd[s].z}, Q1={qd[s].y,qd[s].w};
            v2f P0={pd[s].x,pd[s].z}, P1={pd[s].y,pd[s].w};
            accum_sample2(Q0,Q1,P0,P1,
                t1_00,t1_01,t1_10,t1_11,t2_00,t2_01,t2_10,t2_11,b2_0,b2_1,acc);
        }
    }else{
        for(int j = gtid; j < nv4; j += NT){
            float4 qq = q4[j], pp = p4[j];
            v2f Q0={qq.x,qq.z}, Q1={qq.y,qq.w};
            v2f P0={pp.x,pp.z}, P1={pp.y,pp.w};
            accum_sample2(Q0,Q1,P0,P1,
                t1_00,t1_01,t1_10,t1_11,t2_00,t2_01,t2_10,t2_11,b2_0,b2_1,acc);
        }
    }

    // DPP wave reduction (VALU pipe), lane 63 holds each wave's total
    const int wave = tid >> 6;
    float wres[36];
    #pragma unroll
    for(int j=0;j<36;j++) wres[j] = wave_sum64(acc[j].x + acc[j].y);
    if((tid & 63) == 63){
        #pragma unroll
        for(int j=0;j<36;j++) red[wave][j] = wres[j];
    }
    __syncthreads();
    if(tid < 36){
        float sum = 0.f;
        #pragma unroll
        for(int w=0; w<RTPB/64; w++) sum += red[w][tid];
        part_out[tid*NBR + blockIdx.x] = sum;
    }
}

// fold all [21][36][NBR] partials (wave-per-segment, coalesced) + 12-dim
// adjoint recursion + pack pk[k] = {T1,T2,b2, Lam1_{k+1},Lam2_{k+1},lb2_{k+1}}
__global__ __launch_bounds__(1024) void k_backfold(
    const float* __restrict__ part,
    const float* __restrict__ thetaAll,
    const float* __restrict__ invK, const float* __restrict__ invKb,
    float* __restrict__ pk_g, float c)
{
    const int tid = threadIdx.x;
    const int wave = tid >> 6, lane = tid & 63;
    __shared__ float sums[(NIT+1)*36];
    __shared__ float ks[16], ksb[4];
    if(tid < 16) ks[tid]  = 0.5f*(invK[tid]  + invK[(tid&3)*4 + (tid>>2)]);
    if(tid < 4)  ksb[tid] = 0.5f*(invKb[tid] + invKb[(tid&1)*2 + (tid>>1)]);

    for(int seg = wave; seg < (NIT+1)*36; seg += 16){
        const float* base = part + (size_t)seg*NBR;
        float s = 0.f;
        #pragma unroll
        for(int i = 0; i < NBR/64; i++) s += base[lane + i*64];
        s = wave_sum64(s);
        if(lane == 63) sums[seg] = s;
    }
    __syncthreads();

    if(tid == 0){
        float lv[12];
        compute_grad(sums + 20*36, thetaAll + 20*12, ks, ksb, c, lv);
        for(int k=NIT-1;k>=0;k--){
            const float* s = sums + k*36;
            const float* T = thetaAll + k*12;
            float* P = pk_g + k*20;
            P[0]=T[0]; P[1]=T[1]; P[2]=T[2]; P[3]=T[3];
            P[4]=T[6]; P[5]=T[7]; P[6]=T[8]; P[7]=T[9];
            P[8]=T[10]; P[9]=T[11];
            P[10]=lv[0]; P[11]=lv[1]; P[12]=lv[2]; P[13]=lv[3];
            P[14]=lv[6]; P[15]=lv[7]; P[16]=lv[8]; P[17]=lv[9];
            P[18]=lv[10]; P[19]=lv[11];
            float H[12];
            for(int a=0;a<2;a++)for(int b=0;b<2;b++){
                int j=a*2+b;
                float data = s[12+a*4+b*2+0]*lv[6+b*2+0]
                           + s[12+a*4+b*2+1]*lv[6+b*2+1]
                           + s[20+a*2+b]*lv[10+b];
                float kv=0.f;
                for(int m=0;m<4;m++) kv += ks[j*4+m]*lv[m];
                H[j]=kv - c*data;
            }
            H[4] = ksb[0]*lv[4] + ksb[1]*lv[5];
            H[5] = ksb[2]*lv[4] + ksb[3]*lv[5];
            for(int cc=0;cc<2;cc++)for(int d=0;d<2;d++){
                int j=cc*2+d;
                float term1 = lv[0+cc]*s[12+0*4+cc*2+d] + lv[2+cc]*s[12+1*4+cc*2+d];
                float term2 = lv[6+cc*2+0]*s[24+cc*3+(0+d)] + lv[6+cc*2+1]*s[24+cc*3+(1+d)];
                float term3 = lv[10+cc]*s[30+cc*2+d];
                float kv=0.f;
                for(int m=0;m<4;m++) kv += ks[j*4+m]*lv[6+m];
                H[6+j]=kv - c*(term1+term2+term3);
            }
            for(int cc=0;cc<2;cc++){
                float z1 = lv[0+cc]*s[20+0*2+cc] + lv[2+cc]*s[20+1*2+cc];
                float z2 = lv[6+cc*2+0]*s[30+cc*2+0] + lv[6+cc*2+1]*s[30+cc*2+1];
                float z3 = lv[10+cc]*s[34+cc];
                float kv = ksb[cc*2+0]*lv[10] + ksb[cc*2+1]*lv[11];
                H[10+cc]=kv - c*(z1+z2+z3);
            }
            for(int j=0;j<12;j++) lv[j] -= LR*H[j];
        }
    }
}

__device__ __forceinline__ void bk_step2(v2f Q0, v2f Q1, v2f P0, v2f P1,
    float t1_00,float t1_01,float t1_10,float t1_11,
    float t2_00,float t2_01,float t2_10,float t2_11,float b2_0,float b2_1,
    float L1_00,float L1_01,float L1_10,float L1_11,
    float L2_00,float L2_01,float L2_10,float L2_11,float lb2_0,float lb2_1,
    v2f &B0, v2f &B1){
    v2f u0 = t2_00*Q0 + t2_01*Q1 + b2_0;
    v2f u1 = t2_10*Q0 + t2_11*Q1 + b2_1;
    v2f h0 = tanh2(u0), h1 = tanh2(u1);
    v2f s0 = 1.0f - h0*h0, s1 = 1.0f - h1*h1;
    v2f a0 = t1_00*P0 + t1_10*P1;
    v2f a1 = t1_01*P0 + t1_11*P1;
    v2f w0 = a0*s0, w1 = a1*s1;
    v2f r0 = -2.0f*(a0*h0)*s0, r1 = -2.0f*(a1*h1)*s1;
    v2f lp0 = L1_00*P0 + L1_10*P1;
    v2f lp1 = L1_01*P0 + L1_11*P1;
    v2f z0 = L2_00*Q0 + L2_01*Q1 + lb2_0;
    v2f z1 = L2_10*Q0 + L2_11*Q1 + lb2_1;
    v2f m0 = lp0*s0 + r0*z0;
    v2f m1 = lp1*s1 + r1*z1;
    B0 += t2_00*m0 + t2_10*m1 + L2_00*w0 + L2_10*w1;
    B1 += t2_01*m0 + t2_11*m1 + L2_01*w0 + L2_11*w1;
}

__global__ __launch_bounds__(256) void k_final(
    const float4* __restrict__ q4, const float4* __restrict__ p4,
    const float4* __restrict__ x4, int nv4,
    const float4* __restrict__ pk4,       // [NIT][5]
    const float4* __restrict__ th20_4,    // [3] theta row 20
    float4* __restrict__ oq, float4* __restrict__ op, float4* __restrict__ ox,
    float c)
{
    __shared__ float4 pkS[NIT*5];
    __shared__ float4 t20[3];
    for(int j=threadIdx.x;j<NIT*5;j+=blockDim.x) pkS[j]=pk4[j];
    if(threadIdx.x<3) t20[threadIdx.x]=th20_4[threadIdx.x];
    __syncthreads();

    const int NT = gridDim.x*blockDim.x;
    const int j1 = blockIdx.x*blockDim.x + threadIdx.x;
    const int j2 = j1 + NT;
    const bool v1 = (j1 < nv4), v2 = (j2 < nv4);

    v2f Q0a,Q1a,P0a,P1a, Q0b,Q1b,P0b,P1b;
    if(v1){ float4 qq=q4[j1], pp=p4[j1];
        Q0a=(v2f){qq.x,qq.z}; Q1a=(v2f){qq.y,qq.w};
        P0a=(v2f){pp.x,pp.z}; P1a=(v2f){pp.y,pp.w}; }
    if(v2){ float4 qq=q4[j2], pp=p4[j2];
        Q0b=(v2f){qq.x,qq.z}; Q1b=(v2f){qq.y,qq.w};
        P0b=(v2f){pp.x,pp.z}; P1b=(v2f){pp.y,pp.w}; }

    v2f B0a={0.f,0.f},B1a={0.f,0.f},B0b={0.f,0.f},B1b={0.f,0.f};
    #pragma unroll 4
    for(int k=0;k<NIT;k++){
        float4 P0=pkS[k*5+0], P1=pkS[k*5+1], P2=pkS[k*5+2], P3=pkS[k*5+3], P4v=pkS[k*5+4];
        float t1_00=P0.x,t1_01=P0.y,t1_10=P0.z,t1_11=P0.w;
        float t2_00=P1.x,t2_01=P1.y,t2_10=P1.z,t2_11=P1.w;
        float b2_0=P2.x,b2_1=P2.y;
        float L1_00=P2.z,L1_01=P2.w,L1_10=P3.x,L1_11=P3.y;
        float L2_00=P3.z,L2_01=P3.w,L2_10=P4v.x,L2_11=P4v.y,lb2_0=P4v.z,lb2_1=P4v.w;
        if(v1) bk_step2(Q0a,Q1a,P0a,P1a,
                t1_00,t1_01,t1_10,t1_11,t2_00,t2_01,t2_10,t2_11,b2_0,b2_1,
                L1_00,L1_01,L1_10,L1_11,L2_00,L2_01,L2_10,L2_11,lb2_0,lb2_1,B0a,B1a);
        if(v2) bk_step2(Q0b,Q1b,P0b,P1b,
                t1_00,t1_01,t1_10,t1_11,t2_00,t2_01,t2_10,t2_11,b2_0,b2_1,
                L1_00,L1_01,L1_10,L1_11,L2_00,L2_01,L2_10,L2_11,lb2_0,lb2_1,B0b,B1b);
    }

    float4 Ta=t20[0], Tb=t20[1], Tc=t20[2];
    float t1_00=Ta.x,t1_01=Ta.y,t1_10=Ta.z,t1_11=Ta.w,b1_0=Tb.x,b1_1=Tb.y;
    float t2_00=Tb.z,t2_01=Tb.w,t2_10=Tc.x,t2_11=Tc.y,b2_0=Tc.z,b2_1=Tc.w;

    #pragma unroll
    for(int sl=0; sl<2; sl++){
        bool v = sl? v2 : v1;
        if(!v) continue;
        int j = sl? j2 : j1;
        v2f Q0 = sl? Q0b:Q0a, Q1 = sl? Q1b:Q1a, P0 = sl? P0b:P0a, P1 = sl? P1b:P1a;
        v2f Bs0 = sl? B0b:B0a, Bs1 = sl? B1b:B1a;
        v2f u0 = t2_00*Q0 + t2_01*Q1 + b2_0;
        v2f u1 = t2_10*Q0 + t2_11*Q1 + b2_1;
        v2f h0 = tanh2(u0), h1 = tanh2(u1);
        v2f s0 = 1.0f - h0*h0, s1 = 1.0f - h1*h1;
        v2f a0 = t1_00*P0 + t1_10*P1;
        v2f a1 = t1_01*P0 + t1_11*P1;
        v2f w0 = a0*s0, w1 = a1*s1;
        v2f dq0 = t1_00*h0 + t1_01*h1 + b1_0;
        v2f dq1 = t1_10*h0 + t1_11*h1 + b1_1;
        v2f dp0 = c*(LR*Bs0 - (t2_00*w0 + t2_10*w1));
        v2f dp1 = c*(LR*Bs1 - (t2_01*w0 + t2_11*w1));
        oq[j] = make_float4(dq0.x, dq1.x, dq0.y, dq1.y);
        op[j] = make_float4(dp0.x, dp1.x, dp0.y, dp1.y);
        float4 xx = x4[j];
        v2f X0={xx.x,xx.z}, X1={xx.y,xx.w};
        v2f xu0 = t2_00*X0 + t2_01*X1 + b2_0;
        v2f xu1 = t2_10*X0 + t2_11*X1 + b2_1;
        v2f xh0 = tanh2(xu0), xh1 = tanh2(xu1);
        v2f xd0 = t1_00*xh0 + t1_01*xh1 + b1_0;
        v2f xd1 = t1_10*xh0 + t1_11*xh1 + b1_1;
        ox[j] = make_float4(xd0.x, xd1.x, xd0.y, xd1.y);
    }
}

extern "C" void kernel_launch(void* const* d_in, const int* in_sizes, int n_in,
                              void* d_out, int out_size, void* d_ws, size_t ws_size,
                              hipStream_t stream) {
    const float* inp = (const float*)d_in[1];
    const int K = in_sizes[1]/6;
    const int nv4 = K >> 1;

    const float4* q4 = (const float4*)inp;
    const float4* p4 = (const float4*)(inp + 2*(size_t)K);
    const float4* x4 = (const float4*)(inp + 4*(size_t)K);

    float* part  = (float*)d_ws;                                   // [21][36][NBR]
    float* theta = part + (size_t)(NIT+1)*36*NBR;                  // [21][12]
    float* pk    = theta + 252;                                    // [20][20]
    const float c = 1.0f/(2.0f*(float)K);

    const float* t1i = (const float*)d_in[2];
    const float* b1i = (const float*)d_in[3];
    const float* t2i = (const float*)d_in[4];
    const float* b2i = (const float*)d_in[5];
    const float* invK = (const float*)d_in[6];
    const float* invKb= (const float*)d_in[7];

    for(int k=0;k<=NIT;k++){
        const float* th_prev = (k==0) ? nullptr : theta + (k-1)*12;
        const float* pt_prev = (k==0) ? nullptr : part + (size_t)(k-1)*36*NBR;
        k_reduce<<<NBR,RTPB,0,stream>>>(q4, p4, nv4,
                                        t1i, b1i, t2i, b2i, invK, invKb,
                                        th_prev, pt_prev,
                                        part + (size_t)k*36*NBR, theta + k*12, c);
    }
    k_backfold<<<1,1024,0,stream>>>(part, theta, invK, invKb, pk, c);

    float* out = (float*)d_out;
    int fthreads = (nv4 + 1)/2;
    int fblk = (fthreads + 255)/256;
    k_final<<<fblk,256,0,stream>>>(q4, p4, x4, nv4,
                                   (const float4*)pk, (const float4*)(theta + NIT*12),
                                   (float4*)out, (float4*)(out + 2*(size_t)K),
                                   (float4*)(out + 4*(size_t)K), c);
}